// Round 12
// baseline (3010.248 us; speedup 1.0000x reference)
//
#include <hip/hip_runtime.h>

#define BATCH 32

__device__ __forceinline__ float4 ld4(const float* p) { return *(const float4*)p; }

// ===========================================================================
// conv64_v2 (pre1, pre2, l1a, l1b): stride-1 3x3, Ci=Co=64, H=W (32/16).
// 128-thread blocks (2 waves = 2 co-octets); cg covers 4 groups of 16 co ->
// 2x block count vs round 11 at identical total waves (wave-supply fix:
// Occ was 25% at 1024x256). Weights wave-uniform s_loads. KS-way ci split;
// partials to pbuf[ks][b][co][h][w]. NCH==2 (KS=4, H=32): software-pipelined
// staging (chunk-1 global loads prefetched into registers during chunk-0).
// ===========================================================================
template<int H, int KS>
__global__ __launch_bounds__(128) void conv64_v2(
    const float* __restrict__ in, const float* __restrict__ w,
    float* __restrict__ pbuf)
{
    constexpr int W    = H;
    constexpr int QR   = W / 4;
    constexpr int ROWS = 64 / QR;
    constexpr int RS   = W + 4;
    constexpr int CCT  = 64 / KS;
    constexpr int CC   = (CCT < 8) ? CCT : 8;
    constexpr int NCH  = CCT / CC;
    constexpr int PLANE = (ROWS + 2) * RS;
    constexpr int NTOT = 32 * 64 * H * W;
    constexpr int LCNT = CC * (ROWS + 2) * (W + 2);
    constexpr int NT   = 128;
    static_assert(NCH == 1 || NCH == 2, "pipeline supports <=2 chunks");
    __shared__ float sIn[CC * PLANE];

    const int tid  = threadIdx.x;
    const int b    = blockIdx.x;
    const int rt   = blockIdx.y;
    const int zc   = blockIdx.z;
    const int cg   = zc & 3;                  // co quarter (16 co)
    const int ks   = zc >> 2;                 // ci chunk id
    const int lane = tid & 63;
    const int g    = __builtin_amdgcn_readfirstlane(tid >> 6);  // 0..1
    const int octet = cg * 16 + g * 8;        // wave-uniform co base
    const int r    = lane / QR;
    const int wq   = lane % QR;
    const int ho   = rt * ROWS + r;
    const int row0 = rt * ROWS;

    float acc[8][4] = {};
    const size_t in_b = (size_t)b * 64 * H * W;

    auto stage_off = [&](int i) -> int {
        int c   = i / ((ROWS + 2) * (W + 2));
        int rr  = (i / (W + 2)) % (ROWS + 2);
        int col = i % (W + 2);
        return c * PLANE + rr * RS + col;
    };
    auto stage_val = [&](int i, int c0) -> float {
        int c   = i / ((ROWS + 2) * (W + 2));
        int rr  = (i / (W + 2)) % (ROWS + 2);
        int col = i % (W + 2);
        int ih  = row0 + rr - 1;
        int iw  = col - 1;
        float v = 0.f;
        if ((unsigned)ih < (unsigned)H && (unsigned)iw < (unsigned)W)
            v = in[in_b + (size_t)(c0 + c) * H * W + ih * W + iw];
        return v;
    };

    auto compute_chunk = [&](int c0) {
        for (int c = 0; c < CC; ++c) {
            float rv[3][6];
            #pragma unroll
            for (int dr = 0; dr < 3; ++dr) {
                const float* p = &sIn[c * PLANE + (r + dr) * RS + wq * 4];
                float4 a  = ld4(p);
                float2 b2 = *(const float2*)(p + 4);
                rv[dr][0] = a.x;  rv[dr][1] = a.y; rv[dr][2] = a.z; rv[dr][3] = a.w;
                rv[dr][4] = b2.x; rv[dr][5] = b2.y;
            }
            const float* wc = w + ((size_t)octet * 64 + (c0 + c)) * 9;
            #pragma unroll
            for (int j = 0; j < 8; ++j) {
                const float* wk = wc + (size_t)j * 64 * 9;  // wave-uniform -> s_load
                float w0 = wk[0], w1 = wk[1], w2 = wk[2];
                float w3 = wk[3], w4 = wk[4], w5 = wk[5];
                float w6 = wk[6], w7 = wk[7], w8 = wk[8];
                #pragma unroll
                for (int k = 0; k < 4; ++k) {
                    acc[j][k] = fmaf(rv[0][k + 0], w0, acc[j][k]);
                    acc[j][k] = fmaf(rv[0][k + 1], w1, acc[j][k]);
                    acc[j][k] = fmaf(rv[0][k + 2], w2, acc[j][k]);
                    acc[j][k] = fmaf(rv[1][k + 0], w3, acc[j][k]);
                    acc[j][k] = fmaf(rv[1][k + 1], w4, acc[j][k]);
                    acc[j][k] = fmaf(rv[1][k + 2], w5, acc[j][k]);
                    acc[j][k] = fmaf(rv[2][k + 0], w6, acc[j][k]);
                    acc[j][k] = fmaf(rv[2][k + 1], w7, acc[j][k]);
                    acc[j][k] = fmaf(rv[2][k + 2], w8, acc[j][k]);
                }
            }
        }
    };

    if constexpr (NCH == 1) {
        for (int i = tid; i < LCNT; i += NT)
            sIn[stage_off(i)] = stage_val(i, ks * CCT);
        __syncthreads();
        compute_chunk(ks * CCT);
    } else {
        for (int i = tid; i < LCNT; i += NT)
            sIn[stage_off(i)] = stage_val(i, ks * CCT);
        constexpr int PF = (LCNT + NT - 1) / NT;
        float pf[PF];
        #pragma unroll
        for (int k = 0; k < PF; ++k) {
            int i = tid + k * NT;
            pf[k] = (i < LCNT) ? stage_val(i, ks * CCT + CC) : 0.f;
        }
        __syncthreads();
        compute_chunk(ks * CCT);
        __syncthreads();
        #pragma unroll
        for (int k = 0; k < PF; ++k) {
            int i = tid + k * NT;
            if (i < LCNT) sIn[stage_off(i)] = pf[k];
        }
        __syncthreads();
        compute_chunk(ks * CCT + CC);
    }

    #pragma unroll
    for (int j = 0; j < 8; ++j) {
        const size_t idx = ((size_t)(b * 64 + octet + j) * H + ho) * W + wq * 4;
        *(float4*)&pbuf[(size_t)ks * NTOT + idx] =
            make_float4(acc[j][0], acc[j][1], acc[j][2], acc[j][3]);
    }
}

// ===========================================================================
// conv_mid (l2a): CI->CO stride-2 3x3, 16 -> 8x8. KS=32 (CC=2).
// ===========================================================================
template<int CI, int CO, int KS, int RT>
__global__ __launch_bounds__(256) void conv_mid(
    const float* __restrict__ in, const float* __restrict__ w,
    float* __restrict__ pbuf)
{
    constexpr int HIN = 16, HOUT = 8;
    constexpr int CC  = CI / KS;
    constexpr int NR  = (RT - 1) * 2 + 3;
    constexpr int BSTR = NR * HIN + 4;
    constexpr int CST  = 32 * BSTR;
    constexpr int NTOT = 32 * CO * HOUT * HOUT;
    __shared__ float sBuf[CC * CST];

    const int tid  = threadIdx.x;
    const int lane = tid & 63;
    const int b    = lane >> 1;
    const int ks   = blockIdx.x;
    const int co_u = __builtin_amdgcn_readfirstlane(blockIdx.y * 4 + (tid >> 6));
    const int r0   = blockIdx.z * RT;
    const int g0   = r0 * 2 - 1;

    for (int i = tid; i < CC * 32 * NR * 4; i += 256) {
        int q  = i % 4;
        int s  = (i / 4) % NR;
        int bb = (i / (4 * NR)) % 32;
        int c  = i / (4 * NR * 32);
        int gr = g0 + s;
        float4 v = make_float4(0.f, 0.f, 0.f, 0.f);
        if ((unsigned)gr < (unsigned)HIN)
            v = ld4(&in[(((size_t)bb * CI + ks * CC + c) * HIN + gr) * HIN + q * 4]);
        *(float4*)&sBuf[c * CST + bb * BSTR + s * HIN + q * 4] = v;
    }
    __syncthreads();

    float acc[RT * 8] = {};
    #pragma unroll
    for (int c = 0; c < CC; ++c) {
        const float* wk = w + ((size_t)co_u * CI + ks * CC + c) * 9;  // s_load
        float wr[9];
        #pragma unroll
        for (int q = 0; q < 9; ++q) wr[q] = wk[q];
        float pl[NR * HIN];
        #pragma unroll
        for (int k = 0; k < NR * 4; ++k) {
            float4 v = ld4(&sBuf[c * CST + b * BSTR + k * 4]);
            pl[k * 4 + 0] = v.x; pl[k * 4 + 1] = v.y;
            pl[k * 4 + 2] = v.z; pl[k * 4 + 3] = v.w;
        }
        #pragma unroll
        for (int j = 0; j < RT; ++j) {
            #pragma unroll
            for (int ow = 0; ow < 8; ++ow) {
                #pragma unroll
                for (int kh = 0; kh < 3; ++kh) {
                    const int s = 2 * j + kh;
                    #pragma unroll
                    for (int kw = 0; kw < 3; ++kw) {
                        const int iw = 2 * ow - 1 + kw;
                        if (iw < 0 || iw >= HIN) continue;
                        acc[j * 8 + ow] = fmaf(pl[s * HIN + iw], wr[kh * 3 + kw],
                                               acc[j * 8 + ow]);
                    }
                }
            }
        }
    }

    if ((lane & 1) == 0) {
        #pragma unroll
        for (int j = 0; j < RT; ++j) {
            const size_t idx = ((size_t)(b * CO + co_u) * HOUT + r0 + j) * HOUT;
            *(float4*)&pbuf[(size_t)ks * NTOT + idx] =
                make_float4(acc[j * 8 + 0], acc[j * 8 + 1], acc[j * 8 + 2], acc[j * 8 + 3]);
            *(float4*)&pbuf[(size_t)ks * NTOT + idx + 4] =
                make_float4(acc[j * 8 + 4], acc[j * 8 + 5], acc[j * 8 + 6], acc[j * 8 + 7]);
        }
    }
}

// ===========================================================================
// conv_l2b: 128->128 @8x8 stride1 + 1x1/s2 shortcut. KS=16/CC=8 (measured
// best). Shortcut global loads register-prefetched before main compute so
// the third global-latency phase is hidden under the FMA loop.
// ===========================================================================
template<int KS>
__global__ __launch_bounds__(256) void conv_l2b(
    const float* __restrict__ in,      // [32,128,8,8]
    const float* __restrict__ w,       // [128,128,3,3]
    const float* __restrict__ sc_in,   // [32,64,16,16]
    const float* __restrict__ sc_w,    // [128,64]
    float* __restrict__ pbuf)
{
    constexpr int CI = 128, CO = 128, SC_CI = 64;
    constexpr int CC  = CI / KS;
    constexpr int SCC = SC_CI / KS;
    constexpr int BSTR = 52, CST = 32 * BSTR;
    constexpr int BSTRs = 36, CSTs = 32 * BSTRs;
    constexpr int NTOT = 32 * CO * 64;
    constexpr int NSC  = SCC * 32 * 16;         // float4 count (2048 @ KS=16)
    constexpr int PFS  = (NSC + 255) / 256;     // 8
    __shared__ float sBuf[CC * CST];

    const int tid  = threadIdx.x;
    const int lane = tid & 63;
    const int b    = lane >> 1;
    const int co_u = __builtin_amdgcn_readfirstlane(blockIdx.y * 4 + (tid >> 6));
    const int ks   = blockIdx.x;
    const int r0   = blockIdx.z * 4;

    for (int i = tid; i < CC * 32 * 12; i += 256) {
        int f4  = i % 2;
        int row = (i / 2) % 6;
        int bb  = (i / 12) % 32;
        int c   = i / 384;
        int gr  = r0 - 1 + row;
        float4 v = make_float4(0.f, 0.f, 0.f, 0.f);
        if ((unsigned)gr < 8u)
            v = ld4(&in[(((size_t)bb * CI + ks * CC + c) * 8 + gr) * 8 + f4 * 4]);
        *(float4*)&sBuf[c * CST + bb * BSTR + row * 8 + f4 * 4] = v;
    }
    // issue shortcut global loads now (latency hidden under main compute)
    float4 scpf[PFS];
    #pragma unroll
    for (int k = 0; k < PFS; ++k) {
        int i = tid + k * 256;
        int q   = i % 4;
        int row = (i / 4) % 4;
        int bb  = (i / 16) % 32;
        int c   = i / 512;
        scpf[k] = ld4(&sc_in[
            (((size_t)bb * SC_CI + ks * SCC + c) * 16 + 2 * (r0 + row)) * 16 + q * 4]);
    }
    __syncthreads();

    float acc[32] = {};
    #pragma unroll 2
    for (int c = 0; c < CC; ++c) {
        const float* wk = w + ((size_t)co_u * CI + ks * CC + c) * 9;  // s_load
        float wr[9];
        #pragma unroll
        for (int q = 0; q < 9; ++q) wr[q] = wk[q];
        float pl[48];
        #pragma unroll
        for (int k = 0; k < 12; ++k) {
            float4 v = ld4(&sBuf[c * CST + b * BSTR + k * 4]);
            pl[k * 4 + 0] = v.x; pl[k * 4 + 1] = v.y;
            pl[k * 4 + 2] = v.z; pl[k * 4 + 3] = v.w;
        }
        #pragma unroll
        for (int oh = 0; oh < 4; ++oh) {
            #pragma unroll
            for (int ow = 0; ow < 8; ++ow) {
                #pragma unroll
                for (int kh = 0; kh < 3; ++kh) {
                    #pragma unroll
                    for (int kw = 0; kw < 3; ++kw) {
                        const int iw = ow - 1 + kw;
                        if (iw < 0 || iw >= 8) continue;
                        acc[oh * 8 + ow] = fmaf(pl[(oh + kh) * 8 + iw],
                                                wr[kh * 3 + kw], acc[oh * 8 + ow]);
                    }
                }
            }
        }
    }
    __syncthreads();

    // write prefetched shortcut values into (aliased) LDS, compacted
    #pragma unroll
    for (int k = 0; k < PFS; ++k) {
        int i = tid + k * 256;
        int q   = i % 4;
        int row = (i / 4) % 4;
        int bb  = (i / 16) % 32;
        int c   = i / 512;
        sBuf[c * CSTs + bb * BSTRs + row * 8 + q * 2 + 0] = scpf[k].x;
        sBuf[c * CSTs + bb * BSTRs + row * 8 + q * 2 + 1] = scpf[k].z;
    }
    __syncthreads();

    #pragma unroll
    for (int c = 0; c < SCC; ++c) {
        float sw = sc_w[(size_t)co_u * SC_CI + ks * SCC + c];   // s_load
        #pragma unroll
        for (int p4 = 0; p4 < 8; ++p4) {
            float4 v = ld4(&sBuf[c * CSTs + b * BSTRs + p4 * 4]);
            acc[p4 * 4 + 0] = fmaf(v.x, sw, acc[p4 * 4 + 0]);
            acc[p4 * 4 + 1] = fmaf(v.y, sw, acc[p4 * 4 + 1]);
            acc[p4 * 4 + 2] = fmaf(v.z, sw, acc[p4 * 4 + 2]);
            acc[p4 * 4 + 3] = fmaf(v.w, sw, acc[p4 * 4 + 3]);
        }
    }

    if ((lane & 1) == 0) {
        #pragma unroll
        for (int oh = 0; oh < 4; ++oh) {
            const size_t idx = ((size_t)(b * CO + co_u) * 8 + r0 + oh) * 8;
            *(float4*)&pbuf[(size_t)ks * NTOT + idx]     =
                make_float4(acc[oh * 8 + 0], acc[oh * 8 + 1], acc[oh * 8 + 2], acc[oh * 8 + 3]);
            *(float4*)&pbuf[(size_t)ks * NTOT + idx + 4] =
                make_float4(acc[oh * 8 + 4], acc[oh * 8 + 5], acc[oh * 8 + 6], acc[oh * 8 + 7]);
        }
    }
}

// ===========================================================================
// conv_ks (l3a/l3b/l4a/l4b): K-SPLIT small-plane conv.
// ===========================================================================
template<int CI, int HIN, int STRIDE, int CO, int SC_CI, int SC_HIN,
         int KS, int COB>
__global__ __launch_bounds__(COB * 64) void conv_ks(
    const float* __restrict__ in, const float* __restrict__ w,
    const float* __restrict__ sc_in, const float* __restrict__ sc_w,
    float* __restrict__ pbuf)
{
    constexpr int NT   = COB * 64;
    constexpr int HOUT = (STRIDE == 2) ? HIN / 2 : HIN;
    constexpr int P    = HOUT * HOUT;
    constexpr int NPIX = HIN * HIN;
    constexpr int CC   = CI / KS;
    constexpr int SCC  = (SC_CI > 0) ? SC_CI / KS : 0;
    constexpr int BSTR = NPIX + (((NPIX / 4) % 2 == 0) ? 4 : 0);
    constexpr int CST  = 32 * BSTR;
    constexpr int BSTRs = P + (((P / 4) % 2 == 0) ? 4 : 0);
    constexpr int CSTs  = 32 * BSTRs;
    static_assert(CI % KS == 0, "ks split");
    static_assert(NPIX % 4 == 0 && P % 4 == 0, "vector widths");

    __shared__ float sIn[CC * CST];
    __shared__ float sSc[(SCC > 0) ? SCC * CSTs : 1];

    const int tid  = threadIdx.x;
    const int lane = tid & 63;
    const int b    = lane >> 1;
    const int ks   = blockIdx.x;
    const int co_u = __builtin_amdgcn_readfirstlane(blockIdx.y * COB + (tid >> 6));
    const int cb   = ks * CC;

    constexpr int NF4 = CC * 32 * (NPIX / 4);
    for (int i = tid; i < NF4; i += NT) {
        int k4 = i % (NPIX / 4);
        int c  = (i / (NPIX / 4)) % CC;
        int bb = i / ((NPIX / 4) * CC);
        float4 v = ld4(&in[((size_t)bb * CI + cb + c) * NPIX + k4 * 4]);
        *(float4*)&sIn[c * CST + bb * BSTR + k4 * 4] = v;
    }
    if constexpr (SCC > 0) {
        constexpr int NH  = HOUT / 2;
        constexpr int NSC = SCC * 32 * HOUT * NH;
        for (int i = tid; i < NSC; i += NT) {
            int hc = i % NH;
            int r  = (i / NH) % HOUT;
            int c  = (i / (NH * HOUT)) % SCC;
            int bb = i / (NH * HOUT * SCC);
            float4 v = ld4(&sc_in[
                ((size_t)(bb * SC_CI + ks * SCC + c) * SC_HIN + 2 * r) * SC_HIN
                + hc * 4]);
            sSc[c * CSTs + bb * BSTRs + r * HOUT + hc * 2 + 0] = v.x;
            sSc[c * CSTs + bb * BSTRs + r * HOUT + hc * 2 + 1] = v.z;
        }
    }
    __syncthreads();

    float acc[P] = {};

    const float* wbase = w + ((size_t)co_u * CI + cb) * 9;
    #pragma unroll 4
    for (int j = 0; j < CC; ++j) {
        float wr[9];
        #pragma unroll
        for (int q = 0; q < 9; ++q) wr[q] = wbase[j * 9 + q];
        float plane[NPIX];
        #pragma unroll
        for (int r4 = 0; r4 < NPIX / 4; ++r4) {
            float4 v = ld4(&sIn[j * CST + b * BSTR + r4 * 4]);
            plane[r4 * 4 + 0] = v.x; plane[r4 * 4 + 1] = v.y;
            plane[r4 * 4 + 2] = v.z; plane[r4 * 4 + 3] = v.w;
        }
        #pragma unroll
        for (int ho = 0; ho < HOUT; ++ho) {
            #pragma unroll
            for (int wo = 0; wo < HOUT; ++wo) {
                #pragma unroll
                for (int kh = 0; kh < 3; ++kh) {
                    const int ih = ho * STRIDE - 1 + kh;
                    if (ih < 0 || ih >= HIN) continue;
                    #pragma unroll
                    for (int kw = 0; kw < 3; ++kw) {
                        const int iw = wo * STRIDE - 1 + kw;
                        if (iw < 0 || iw >= HIN) continue;
                        acc[ho * HOUT + wo] =
                            fmaf(plane[ih * HIN + iw], wr[kh * 3 + kw],
                                 acc[ho * HOUT + wo]);
                    }
                }
            }
        }
    }

    if constexpr (SCC > 0) {
        const float* swb = sc_w + (size_t)co_u * SC_CI + ks * SCC;
        #pragma unroll 4
        for (int j = 0; j < SCC; ++j) {
            float sw = swb[j];
            #pragma unroll
            for (int p4 = 0; p4 < P / 4; ++p4) {
                float4 v = ld4(&sSc[j * CSTs + b * BSTRs + p4 * 4]);
                acc[p4 * 4 + 0] = fmaf(v.x, sw, acc[p4 * 4 + 0]);
                acc[p4 * 4 + 1] = fmaf(v.y, sw, acc[p4 * 4 + 1]);
                acc[p4 * 4 + 2] = fmaf(v.z, sw, acc[p4 * 4 + 2]);
                acc[p4 * 4 + 3] = fmaf(v.w, sw, acc[p4 * 4 + 3]);
            }
        }
    }

    if ((lane & 1) == 0) {
        float* pp = pbuf + (((size_t)ks * 32 + b) * CO + co_u) * P;
        #pragma unroll
        for (int p4 = 0; p4 < P / 4; ++p4)
            *(float4*)&pp[p4 * 4] = make_float4(acc[p4 * 4], acc[p4 * 4 + 1],
                                                acc[p4 * 4 + 2], acc[p4 * 4 + 3]);
    }
}

// LIF epilogue on a float4.
__device__ __forceinline__ void lif_store4(
    float4 s, float* __restrict__ mem, const float* __restrict__ mask,
    float* __restrict__ out, float* __restrict__ accum,
    size_t idx, float thr, float leak)
{
    float4 m4 = ld4(&mem[idx]);
    float4 k4 = mask ? ld4(&mask[idx]) : make_float4(1.f, 1.f, 1.f, 1.f);
    float4 mo, oo;
    float m0 = fmaf(leak, m4.x, s.x); float s0 = (m0 / thr - 1.0f > 0.f) ? 1.f : 0.f;
    mo.x = m0 - thr * s0; oo.x = s0 * k4.x;
    float m1 = fmaf(leak, m4.y, s.y); float s1 = (m1 / thr - 1.0f > 0.f) ? 1.f : 0.f;
    mo.y = m1 - thr * s1; oo.y = s1 * k4.y;
    float m2 = fmaf(leak, m4.z, s.z); float s2 = (m2 / thr - 1.0f > 0.f) ? 1.f : 0.f;
    mo.z = m2 - thr * s2; oo.z = s2 * k4.z;
    float m3 = fmaf(leak, m4.w, s.w); float s3 = (m3 / thr - 1.0f > 0.f) ? 1.f : 0.f;
    mo.w = m3 - thr * s3; oo.w = s3 * k4.w;
    *(float4*)&mem[idx] = mo;
    *(float4*)&out[idx] = oo;
    if (accum) {
        float4 a4 = ld4(&accum[idx]);
        a4.x += oo.x; a4.y += oo.y; a4.z += oo.z; a4.w += oo.w;
        *(float4*)&accum[idx] = a4;
    }
}

// Sum KS partials (fixed order) + optional residual + LIF + mask + accum.
template<int CO, int P, int KS>
__global__ __launch_bounds__(256) void reduce_lif(
    const float* __restrict__ pbuf,
    const float* __restrict__ res,
    float* __restrict__ mem,
    const float* __restrict__ thr_a, const float* __restrict__ leak_a, int layer,
    const float* __restrict__ mask, float* __restrict__ out,
    float* __restrict__ accum)
{
    constexpr int TOT4 = 32 * CO * P / 4;
    const int i4 = blockIdx.x * 256 + threadIdx.x;
    if (i4 >= TOT4) return;
    const float4* pb4 = (const float4*)pbuf;
    float4 s = pb4[i4];
    #pragma unroll 4
    for (int ks = 1; ks < KS; ++ks) {
        float4 v = pb4[(size_t)ks * TOT4 + i4];
        s.x += v.x; s.y += v.y; s.z += v.z; s.w += v.w;
    }
    const size_t idx = (size_t)i4 * 4;
    if (res) {
        float4 r4 = ld4(&res[idx]);
        s.x += r4.x; s.y += r4.y; s.z += r4.z; s.w += r4.w;
    }
    lif_store4(s, mem, mask, out, accum, idx, thr_a[layer], leak_a[layer]);
}

// pre2 reducer: reduce KS partials + LIF (no mask) + fused 2x2 avgpool.
template<int KS>
__global__ __launch_bounds__(256) void reduce_lif_pool(
    const float* __restrict__ pbuf, float* __restrict__ mem,
    const float* __restrict__ thr_a, const float* __restrict__ leak_a, int layer,
    float* __restrict__ pool_out)             // [32,64,16,16]
{
    constexpr int TOT = 32 * 64 * 32 * 32;
    const int i = blockIdx.x * 256 + threadIdx.x;
    const int q  = i % 8;
    const int rp = (i / 8) % 16;
    const int c  = (i / 128) % 64;
    const int b  = i / 8192;
    const size_t idx0 = (((size_t)(b * 64 + c) * 32) + 2 * rp) * 32 + 4 * q;
    const size_t idx1 = idx0 + 32;

    float4 s0 = ld4(&pbuf[idx0]);
    float4 s1 = ld4(&pbuf[idx1]);
    #pragma unroll 4
    for (int ks = 1; ks < KS; ++ks) {
        float4 v0 = ld4(&pbuf[(size_t)ks * TOT + idx0]);
        float4 v1 = ld4(&pbuf[(size_t)ks * TOT + idx1]);
        s0.x += v0.x; s0.y += v0.y; s0.z += v0.z; s0.w += v0.w;
        s1.x += v1.x; s1.y += v1.y; s1.z += v1.z; s1.w += v1.w;
    }
    const float thr  = thr_a[layer];
    const float leak = leak_a[layer];
    float4 m0 = ld4(&mem[idx0]), m1 = ld4(&mem[idx1]);
    float4 n0, n1, o0, o1;
    {
        float m = fmaf(leak, m0.x, s0.x); float sp = (m / thr - 1.0f > 0.f) ? 1.f : 0.f;
        n0.x = m - thr * sp; o0.x = sp;
        m = fmaf(leak, m0.y, s0.y); sp = (m / thr - 1.0f > 0.f) ? 1.f : 0.f;
        n0.y = m - thr * sp; o0.y = sp;
        m = fmaf(leak, m0.z, s0.z); sp = (m / thr - 1.0f > 0.f) ? 1.f : 0.f;
        n0.z = m - thr * sp; o0.z = sp;
        m = fmaf(leak, m0.w, s0.w); sp = (m / thr - 1.0f > 0.f) ? 1.f : 0.f;
        n0.w = m - thr * sp; o0.w = sp;
        m = fmaf(leak, m1.x, s1.x); sp = (m / thr - 1.0f > 0.f) ? 1.f : 0.f;
        n1.x = m - thr * sp; o1.x = sp;
        m = fmaf(leak, m1.y, s1.y); sp = (m / thr - 1.0f > 0.f) ? 1.f : 0.f;
        n1.y = m - thr * sp; o1.y = sp;
        m = fmaf(leak, m1.z, s1.z); sp = (m / thr - 1.0f > 0.f) ? 1.f : 0.f;
        n1.z = m - thr * sp; o1.z = sp;
        m = fmaf(leak, m1.w, s1.w); sp = (m / thr - 1.0f > 0.f) ? 1.f : 0.f;
        n1.w = m - thr * sp; o1.w = sp;
    }
    *(float4*)&mem[idx0] = n0;
    *(float4*)&mem[idx1] = n1;
    float2 pv;
    pv.x = (o0.x + o0.y + o1.x + o1.y) * 0.25f;
    pv.y = (o0.z + o0.w + o1.z + o1.w) * 0.25f;
    *(float2*)&pool_out[(((size_t)(b * 64 + c) * 16) + rp) * 16 + 2 * q] = pv;
}

// Merged: l4b reduce (blocks 0..63) + NEXT timestep's lif0 (blocks 64..2111).
template<int KS>
__global__ __launch_bounds__(256) void reduce_l4b_lif0(
    const float* __restrict__ pbuf, float* __restrict__ mem10,
    const float* __restrict__ thr_a, const float* __restrict__ leak_a,
    float* __restrict__ out_s2b, float* __restrict__ ssum,
    const float4* __restrict__ delta, float4* __restrict__ mem0,
    const float4* __restrict__ mask, float4* __restrict__ s32a)
{
    if (blockIdx.x < 64) {
        constexpr int TOT4 = 32 * 512;
        const int i4 = blockIdx.x * 256 + threadIdx.x;
        if (i4 >= TOT4) return;
        const float4* pb4 = (const float4*)pbuf;
        float4 s = pb4[i4];
        #pragma unroll 4
        for (int ks = 1; ks < KS; ++ks) {
            float4 v = pb4[(size_t)ks * TOT4 + i4];
            s.x += v.x; s.y += v.y; s.z += v.z; s.w += v.w;
        }
        lif_store4(s, mem10, nullptr, out_s2b, ssum,
                   (size_t)i4 * 4, thr_a[10], leak_a[10]);
    } else {
        const int i = (blockIdx.x - 64) * 256 + threadIdx.x;
        float thr = thr_a[0], leak = leak_a[0];
        float4 d = delta[i], m4 = mem0[i], k4 = mask[i], mo, oo;
        float m0 = fmaf(leak, m4.x, d.x); float s0 = (m0 / thr - 1.0f > 0.f) ? 1.f : 0.f;
        mo.x = m0 - thr * s0; oo.x = s0 * k4.x;
        float m1 = fmaf(leak, m4.y, d.y); float s1 = (m1 / thr - 1.0f > 0.f) ? 1.f : 0.f;
        mo.y = m1 - thr * s1; oo.y = s1 * k4.y;
        float m2 = fmaf(leak, m4.z, d.z); float s2 = (m2 / thr - 1.0f > 0.f) ? 1.f : 0.f;
        mo.z = m2 - thr * s2; oo.z = s2 * k4.z;
        float m3 = fmaf(leak, m4.w, d.w); float s3 = (m3 / thr - 1.0f > 0.f) ? 1.f : 0.f;
        mo.w = m3 - thr * s3; oo.w = s3 * k4.w;
        mem0[i] = mo; s32a[i] = oo;
    }
}

// ===========================================================================
// Naive direct conv — ONLY for pre0 (Ci=3, runs once per launch).
// ===========================================================================
__global__ __launch_bounds__(256) void conv_raw_kernel(
    const float* __restrict__ in, const float* __restrict__ w,
    float* __restrict__ out,
    int Ci, int Co, int Hin, int Win, int total)
{
    int idx = blockIdx.x * blockDim.x + threadIdx.x;
    if (idx >= total) return;
    int wo = idx % Win;
    int t  = idx / Win;
    int ho = t % Hin; t /= Hin;
    int co = t % Co;
    int b  = t / Co;
    int ih0 = ho - 1, iw0 = wo - 1;
    const float* wp = w + (size_t)co * Ci * 9;
    const float* ip = in + (size_t)b * Ci * Hin * Win;
    bool hv0 = (unsigned)(ih0)     < (unsigned)Hin;
    bool hv1 = (unsigned)(ih0 + 1) < (unsigned)Hin;
    bool hv2 = (unsigned)(ih0 + 2) < (unsigned)Hin;
    bool wv0 = (unsigned)(iw0)     < (unsigned)Win;
    bool wv1 = (unsigned)(iw0 + 1) < (unsigned)Win;
    bool wv2 = (unsigned)(iw0 + 2) < (unsigned)Win;
    float acc = 0.f;
    int plane = Hin * Win;
    for (int ci = 0; ci < Ci; ++ci) {
        const float* irow = ip + ci * plane;
        const float* wk   = wp + ci * 9;
        if (hv0) {
            const float* r = irow + ih0 * Win;
            if (wv0) acc = fmaf(r[iw0],     wk[0], acc);
            if (wv1) acc = fmaf(r[iw0 + 1], wk[1], acc);
            if (wv2) acc = fmaf(r[iw0 + 2], wk[2], acc);
        }
        if (hv1) {
            const float* r = irow + (ih0 + 1) * Win;
            if (wv0) acc = fmaf(r[iw0],     wk[3], acc);
            if (wv1) acc = fmaf(r[iw0 + 1], wk[4], acc);
            if (wv2) acc = fmaf(r[iw0 + 2], wk[5], acc);
        }
        if (hv2) {
            const float* r = irow + (ih0 + 2) * Win;
            if (wv0) acc = fmaf(r[iw0],     wk[6], acc);
            if (wv1) acc = fmaf(r[iw0 + 1], wk[7], acc);
            if (wv2) acc = fmaf(r[iw0 + 2], wk[8], acc);
        }
    }
    out[idx] = acc;
}

// Elementwise LIF for layer 0 — standalone (t=0 only).
__global__ __launch_bounds__(256) void lif0_kernel(
    const float4* __restrict__ delta, float4* __restrict__ mem,
    const float* __restrict__ thr_a, const float* __restrict__ leak_a,
    const float4* __restrict__ mask, float4* __restrict__ out, int total4)
{
    int i = blockIdx.x * blockDim.x + threadIdx.x;
    if (i >= total4) return;
    float thr = thr_a[0], leak = leak_a[0];
    float4 d = delta[i], m4 = mem[i], k4 = mask[i], mo, oo;
    float m0 = fmaf(leak, m4.x, d.x); float s0 = (m0 / thr - 1.0f > 0.f) ? 1.f : 0.f;
    mo.x = m0 - thr * s0; oo.x = s0 * k4.x;
    float m1 = fmaf(leak, m4.y, d.y); float s1 = (m1 / thr - 1.0f > 0.f) ? 1.f : 0.f;
    mo.y = m1 - thr * s1; oo.y = s1 * k4.y;
    float m2 = fmaf(leak, m4.z, d.z); float s2 = (m2 / thr - 1.0f > 0.f) ? 1.f : 0.f;
    mo.z = m2 - thr * s2; oo.z = s2 * k4.z;
    float m3 = fmaf(leak, m4.w, d.w); float s3 = (m3 / thr - 1.0f > 0.f) ? 1.f : 0.f;
    mo.w = m3 - thr * s3; oo.w = s3 * k4.w;
    mem[i] = mo; out[i] = oo;
}

// FC: out[b,k] = dot(spikesum[b, :2048], wfc[k, :2048]). One wave per (b,k).
__global__ __launch_bounds__(64) void fc_kernel(
    const float* __restrict__ s, const float* __restrict__ wfc,
    float* __restrict__ out)
{
    int bk = blockIdx.x;
    int b = bk / 10, k = bk % 10;
    const float* sp = s   + (size_t)b * 2048;
    const float* wp = wfc + (size_t)k * 2048;
    float acc = 0.f;
    for (int j = threadIdx.x; j < 2048; j += 64)
        acc = fmaf(sp[j], wp[j], acc);
    #pragma unroll
    for (int off = 32; off; off >>= 1)
        acc += __shfl_down(acc, off, 64);
    if (threadIdx.x == 0) out[b * 10 + k] = acc;
}

// ---------------------------------------------------------------------------
extern "C" void kernel_launch(void* const* d_in, const int* in_sizes, int n_in,
                              void* d_out, int out_size, void* d_ws, size_t ws_size,
                              hipStream_t stream) {
    const float* x      = (const float*)d_in[0];
    const float* w_pre0 = (const float*)d_in[1];
    const float* w_pre1 = (const float*)d_in[2];
    const float* w_pre2 = (const float*)d_in[3];
    const float* w1a    = (const float*)d_in[4];
    const float* w1b    = (const float*)d_in[5];
    const float* w2a    = (const float*)d_in[6];
    const float* w2b    = (const float*)d_in[7];
    const float* w2i    = (const float*)d_in[8];
    const float* w3a    = (const float*)d_in[9];
    const float* w3b    = (const float*)d_in[10];
    const float* w3i    = (const float*)d_in[11];
    const float* w4a    = (const float*)d_in[12];
    const float* w4b    = (const float*)d_in[13];
    const float* w4i    = (const float*)d_in[14];
    const float* w_fc   = (const float*)d_in[15];
    const float* thr    = (const float*)d_in[16];
    const float* leak   = (const float*)d_in[17];
    const float* mask2  = (const float*)d_in[18];
    const float* mask5  = (const float*)d_in[19];
    const float* mask9  = (const float*)d_in[20];
    const float* mask11 = (const float*)d_in[21];
    const float* mask13 = (const float*)d_in[22];
    const float* mask15 = (const float*)d_in[23];

    // ---- workspace layout (floats) ----
    float* ws = (float*)d_ws;
    size_t off = 0;
    auto alloc = [&](size_t n) { float* p = ws + off; off += n; return p; };
    float* m0  = alloc(2097152);  // 32*64*32*32
    float* m1  = alloc(2097152);
    float* m2  = alloc(2097152);
    float* m3  = alloc(524288);   // 32*64*16*16
    float* m4  = alloc(524288);
    float* m5  = alloc(262144);   // 32*128*8*8
    float* m6  = alloc(262144);
    float* m7  = alloc(131072);   // 32*256*4*4
    float* m8  = alloc(131072);
    float* m9  = alloc(65536);    // 32*512*2*2
    float* m10 = alloc(65536);
    float* ssum = alloc(65536);   // fc spike accumulator (32 x 2048)
    size_t zero_floats = off;
    float* delta0  = alloc(2097152);
    float* s32_a   = alloc(2097152);
    float* s32_b   = alloc(2097152);
    float* s16_inp = alloc(524288);
    float* s16_a   = alloc(524288);
    float* s16_b   = alloc(524288);
    float* s8_a    = alloc(262144);
    float* s8_b    = alloc(262144);
    float* s4_a    = alloc(131072);
    float* s4_b    = alloc(131072);
    float* s2_a    = alloc(65536);
    float* s2_b    = alloc(65536);
    float* pbuf    = alloc(16777216);  // K-split partials
    (void)ws_size; (void)in_sizes; (void)n_in; (void)out_size;

    hipMemsetAsync(d_ws, 0, zero_floats * sizeof(float), stream);

    auto grid = [](int total) { return dim3((total + 255) / 256); };

    // timestep-invariant: delta0 = conv(x, w_pre0)
    {
        int total = BATCH * 64 * 32 * 32;
        conv_raw_kernel<<<grid(total), 256, 0, stream>>>(
            x, w_pre0, delta0, 3, 64, 32, 32, total);
    }

    int n32 = BATCH * 64 * 32 * 32;
    // t=0 lif0 (standalone; t>=1 lif0 is fused into prior l4b reduce)
    lif0_kernel<<<grid(n32 / 4), 256, 0, stream>>>(
        (const float4*)delta0, (float4*)m0, thr, leak,
        (const float4*)mask2, (float4*)s32_a, n32 / 4);

    for (int t = 0; t < 8; ++t) {
        // pre1: 64->64 @32x32 + LIF + mask5  (KS=4, pipelined, 128-thr blocks)
        conv64_v2<32, 4><<<dim3(BATCH, 4, 16), 128, 0, stream>>>(s32_a, w_pre1, pbuf);
        reduce_lif<64, 1024, 4><<<dim3(2048), 256, 0, stream>>>(
            pbuf, nullptr, m1, thr, leak, 1, mask5, s32_b, nullptr);
        // pre2: 64->64 @32x32 + LIF + fused avgpool -> s16_inp
        conv64_v2<32, 4><<<dim3(BATCH, 4, 16), 128, 0, stream>>>(s32_b, w_pre2, pbuf);
        reduce_lif_pool<4><<<dim3(1024), 256, 0, stream>>>(
            pbuf, m2, thr, leak, 2, s16_inp);
        // layer1 a: 64->64 @16x16 + LIF + mask9  (KS=8, 128-thr blocks)
        conv64_v2<16, 8><<<dim3(BATCH, 1, 32), 128, 0, stream>>>(s16_inp, w1a, pbuf);
        reduce_lif<64, 256, 8><<<dim3(512), 256, 0, stream>>>(
            pbuf, nullptr, m3, thr, leak, 3, mask9, s16_a, nullptr);
        // layer1 b: 64->64 @16x16 + identity residual + LIF  (KS=8)
        conv64_v2<16, 8><<<dim3(BATCH, 1, 32), 128, 0, stream>>>(s16_a, w1b, pbuf);
        reduce_lif<64, 256, 8><<<dim3(512), 256, 0, stream>>>(
            pbuf, s16_inp, m4, thr, leak, 4, nullptr, s16_b, nullptr);

        // layer2 a: 64->128 s2 @16->8 + LIF + mask11  (conv_mid, KS=32, RT=2)
        conv_mid<64, 128, 32, 2><<<dim3(32, 32, 4), 256, 0, stream>>>(
            s16_b, w2a, pbuf);
        reduce_lif<128, 64, 32><<<dim3(256), 256, 0, stream>>>(
            pbuf, nullptr, m5, thr, leak, 5, mask11, s8_a, nullptr);
        // layer2 b: 128->128 @8x8 + 1x1/s2 shortcut + LIF  (KS=16, sc prefetch)
        conv_l2b<16><<<dim3(16, 32, 2), 256, 0, stream>>>(
            s8_a, w2b, s16_b, w2i, pbuf);
        reduce_lif<128, 64, 16><<<dim3(256), 256, 0, stream>>>(
            pbuf, nullptr, m6, thr, leak, 6, nullptr, s8_b, nullptr);
        // layer3 a: 128->256 s2 @8->4 + LIF + mask13  (K-split 32)
        conv_ks<128, 8, 2, 256, 0, 0, 32, 4><<<dim3(32, 64), 256, 0, stream>>>(
            s8_b, w3a, nullptr, nullptr, pbuf);
        reduce_lif<256, 16, 32><<<dim3(128), 256, 0, stream>>>(
            pbuf, nullptr, m7, thr, leak, 7, mask13, s4_a, nullptr);
        // layer3 b: 256->256 @4x4 + 1x1/s2 shortcut + LIF  (K-split 16)
        conv_ks<256, 4, 1, 256, 128, 8, 16, 4><<<dim3(16, 64), 256, 0, stream>>>(
            s4_a, w3b, s8_b, w3i, pbuf);
        reduce_lif<256, 16, 16><<<dim3(128), 256, 0, stream>>>(
            pbuf, nullptr, m8, thr, leak, 8, nullptr, s4_b, nullptr);
        // layer4 a: 256->512 s2 @4->2 + LIF + mask15  (K-split 16)
        conv_ks<256, 4, 2, 512, 0, 0, 16, 4><<<dim3(16, 128), 256, 0, stream>>>(
            s4_b, w4a, nullptr, nullptr, pbuf);
        reduce_lif<512, 4, 16><<<dim3(64), 256, 0, stream>>>(
            pbuf, nullptr, m9, thr, leak, 9, mask15, s2_a, nullptr);
        // layer4 b: 512->512 @2x2 + 1x1/s2 shortcut + LIF + spike-sum (K-split 16)
        conv_ks<512, 2, 1, 512, 256, 4, 16, 4><<<dim3(16, 128), 256, 0, stream>>>(
            s2_a, w4b, s4_b, w4i, pbuf);
        if (t < 7) {
            reduce_l4b_lif0<16><<<dim3(64 + 2048), 256, 0, stream>>>(
                pbuf, m10, thr, leak, s2_b, ssum,
                (const float4*)delta0, (float4*)m0, (const float4*)mask2,
                (float4*)s32_a);
        } else {
            reduce_lif<512, 4, 16><<<dim3(64), 256, 0, stream>>>(
                pbuf, nullptr, m10, thr, leak, 10, nullptr, s2_b, ssum);
        }
    }

    // final FC: d_out[b,k] = dot(ssum[b], w_fc[k])
    fc_kernel<<<dim3(320), dim3(64), 0, stream>>>(ssum, w_fc, (float*)d_out);
}

// Round 13
// 2681.938 us; speedup vs baseline: 1.1224x; 1.1224x over previous
//
#include <hip/hip_runtime.h>

#define BATCH 32

__device__ __forceinline__ float4 ld4(const float* p) { return *(const float4*)p; }

// ===========================================================================
// conv64_v2 (pre1, pre2, l1a, l1b): stride-1 3x3, Ci=Co=64, H=W (32/16).
// 256-thread blocks (round-11 config — measured best 41us; 128-thr blocks
// regressed to 56us: per-block halo staging is monolithic, so halving the
// block doubled total staging work and VGPR prefetch pressure).
// Lane = 4 px x 8 co (32 acc); wave = one co-octet -> weights wave-uniform
// s_loads. KS-way ci split; partials to pbuf[ks][b][co][h][w].
// NCH==2 (KS=4, H=32): software-pipelined staging.
// ===========================================================================
template<int H, int KS>
__global__ __launch_bounds__(256) void conv64_v2(
    const float* __restrict__ in, const float* __restrict__ w,
    float* __restrict__ pbuf)
{
    constexpr int W    = H;
    constexpr int QR   = W / 4;
    constexpr int ROWS = 64 / QR;
    constexpr int RS   = W + 4;
    constexpr int CCT  = 64 / KS;
    constexpr int CC   = (CCT < 8) ? CCT : 8;
    constexpr int NCH  = CCT / CC;
    constexpr int PLANE = (ROWS + 2) * RS;
    constexpr int NTOT = 32 * 64 * H * W;
    constexpr int LCNT = CC * (ROWS + 2) * (W + 2);
    static_assert(NCH == 1 || NCH == 2, "pipeline supports <=2 chunks");
    __shared__ float sIn[CC * PLANE];

    const int tid  = threadIdx.x;
    const int b    = blockIdx.x;
    const int rt   = blockIdx.y;
    const int zc   = blockIdx.z;
    const int cg   = zc & 1;                  // co half (32 co)
    const int ks   = zc >> 1;                 // ci chunk id
    const int lane = tid & 63;
    const int g    = __builtin_amdgcn_readfirstlane(tid >> 6);
    const int octet = cg * 32 + g * 8;        // wave-uniform co base
    const int r    = lane / QR;
    const int wq   = lane % QR;
    const int ho   = rt * ROWS + r;
    const int row0 = rt * ROWS;

    float acc[8][4] = {};
    const size_t in_b = (size_t)b * 64 * H * W;

    auto stage_off = [&](int i) -> int {
        int c   = i / ((ROWS + 2) * (W + 2));
        int rr  = (i / (W + 2)) % (ROWS + 2);
        int col = i % (W + 2);
        return c * PLANE + rr * RS + col;
    };
    auto stage_val = [&](int i, int c0) -> float {
        int c   = i / ((ROWS + 2) * (W + 2));
        int rr  = (i / (W + 2)) % (ROWS + 2);
        int col = i % (W + 2);
        int ih  = row0 + rr - 1;
        int iw  = col - 1;
        float v = 0.f;
        if ((unsigned)ih < (unsigned)H && (unsigned)iw < (unsigned)W)
            v = in[in_b + (size_t)(c0 + c) * H * W + ih * W + iw];
        return v;
    };

    auto compute_chunk = [&](int c0) {
        for (int c = 0; c < CC; ++c) {
            float rv[3][6];
            #pragma unroll
            for (int dr = 0; dr < 3; ++dr) {
                const float* p = &sIn[c * PLANE + (r + dr) * RS + wq * 4];
                float4 a  = ld4(p);
                float2 b2 = *(const float2*)(p + 4);
                rv[dr][0] = a.x;  rv[dr][1] = a.y; rv[dr][2] = a.z; rv[dr][3] = a.w;
                rv[dr][4] = b2.x; rv[dr][5] = b2.y;
            }
            const float* wc = w + ((size_t)octet * 64 + (c0 + c)) * 9;
            #pragma unroll
            for (int j = 0; j < 8; ++j) {
                const float* wk = wc + (size_t)j * 64 * 9;  // wave-uniform -> s_load
                float w0 = wk[0], w1 = wk[1], w2 = wk[2];
                float w3 = wk[3], w4 = wk[4], w5 = wk[5];
                float w6 = wk[6], w7 = wk[7], w8 = wk[8];
                #pragma unroll
                for (int k = 0; k < 4; ++k) {
                    acc[j][k] = fmaf(rv[0][k + 0], w0, acc[j][k]);
                    acc[j][k] = fmaf(rv[0][k + 1], w1, acc[j][k]);
                    acc[j][k] = fmaf(rv[0][k + 2], w2, acc[j][k]);
                    acc[j][k] = fmaf(rv[1][k + 0], w3, acc[j][k]);
                    acc[j][k] = fmaf(rv[1][k + 1], w4, acc[j][k]);
                    acc[j][k] = fmaf(rv[1][k + 2], w5, acc[j][k]);
                    acc[j][k] = fmaf(rv[2][k + 0], w6, acc[j][k]);
                    acc[j][k] = fmaf(rv[2][k + 1], w7, acc[j][k]);
                    acc[j][k] = fmaf(rv[2][k + 2], w8, acc[j][k]);
                }
            }
        }
    };

    if constexpr (NCH == 1) {
        for (int i = tid; i < LCNT; i += 256)
            sIn[stage_off(i)] = stage_val(i, ks * CCT);
        __syncthreads();
        compute_chunk(ks * CCT);
    } else {
        for (int i = tid; i < LCNT; i += 256)
            sIn[stage_off(i)] = stage_val(i, ks * CCT);
        constexpr int PF = (LCNT + 255) / 256;
        float pf[PF];
        #pragma unroll
        for (int k = 0; k < PF; ++k) {
            int i = tid + k * 256;
            pf[k] = (i < LCNT) ? stage_val(i, ks * CCT + CC) : 0.f;
        }
        __syncthreads();
        compute_chunk(ks * CCT);
        __syncthreads();
        #pragma unroll
        for (int k = 0; k < PF; ++k) {
            int i = tid + k * 256;
            if (i < LCNT) sIn[stage_off(i)] = pf[k];
        }
        __syncthreads();
        compute_chunk(ks * CCT + CC);
    }

    #pragma unroll
    for (int j = 0; j < 8; ++j) {
        const size_t idx = ((size_t)(b * 64 + octet + j) * H + ho) * W + wq * 4;
        *(float4*)&pbuf[(size_t)ks * NTOT + idx] =
            make_float4(acc[j][0], acc[j][1], acc[j][2], acc[j][3]);
    }
}

// ===========================================================================
// conv_mid (l2a): CI->CO stride-2 3x3, 16 -> 8x8. KS=32 (CC=2).
// ===========================================================================
template<int CI, int CO, int KS, int RT>
__global__ __launch_bounds__(256) void conv_mid(
    const float* __restrict__ in, const float* __restrict__ w,
    float* __restrict__ pbuf)
{
    constexpr int HIN = 16, HOUT = 8;
    constexpr int CC  = CI / KS;
    constexpr int NR  = (RT - 1) * 2 + 3;
    constexpr int BSTR = NR * HIN + 4;
    constexpr int CST  = 32 * BSTR;
    constexpr int NTOT = 32 * CO * HOUT * HOUT;
    __shared__ float sBuf[CC * CST];

    const int tid  = threadIdx.x;
    const int lane = tid & 63;
    const int b    = lane >> 1;
    const int ks   = blockIdx.x;
    const int co_u = __builtin_amdgcn_readfirstlane(blockIdx.y * 4 + (tid >> 6));
    const int r0   = blockIdx.z * RT;
    const int g0   = r0 * 2 - 1;

    for (int i = tid; i < CC * 32 * NR * 4; i += 256) {
        int q  = i % 4;
        int s  = (i / 4) % NR;
        int bb = (i / (4 * NR)) % 32;
        int c  = i / (4 * NR * 32);
        int gr = g0 + s;
        float4 v = make_float4(0.f, 0.f, 0.f, 0.f);
        if ((unsigned)gr < (unsigned)HIN)
            v = ld4(&in[(((size_t)bb * CI + ks * CC + c) * HIN + gr) * HIN + q * 4]);
        *(float4*)&sBuf[c * CST + bb * BSTR + s * HIN + q * 4] = v;
    }
    __syncthreads();

    float acc[RT * 8] = {};
    #pragma unroll
    for (int c = 0; c < CC; ++c) {
        const float* wk = w + ((size_t)co_u * CI + ks * CC + c) * 9;  // s_load
        float wr[9];
        #pragma unroll
        for (int q = 0; q < 9; ++q) wr[q] = wk[q];
        float pl[NR * HIN];
        #pragma unroll
        for (int k = 0; k < NR * 4; ++k) {
            float4 v = ld4(&sBuf[c * CST + b * BSTR + k * 4]);
            pl[k * 4 + 0] = v.x; pl[k * 4 + 1] = v.y;
            pl[k * 4 + 2] = v.z; pl[k * 4 + 3] = v.w;
        }
        #pragma unroll
        for (int j = 0; j < RT; ++j) {
            #pragma unroll
            for (int ow = 0; ow < 8; ++ow) {
                #pragma unroll
                for (int kh = 0; kh < 3; ++kh) {
                    const int s = 2 * j + kh;
                    #pragma unroll
                    for (int kw = 0; kw < 3; ++kw) {
                        const int iw = 2 * ow - 1 + kw;
                        if (iw < 0 || iw >= HIN) continue;
                        acc[j * 8 + ow] = fmaf(pl[s * HIN + iw], wr[kh * 3 + kw],
                                               acc[j * 8 + ow]);
                    }
                }
            }
        }
    }

    if ((lane & 1) == 0) {
        #pragma unroll
        for (int j = 0; j < RT; ++j) {
            const size_t idx = ((size_t)(b * CO + co_u) * HOUT + r0 + j) * HOUT;
            *(float4*)&pbuf[(size_t)ks * NTOT + idx] =
                make_float4(acc[j * 8 + 0], acc[j * 8 + 1], acc[j * 8 + 2], acc[j * 8 + 3]);
            *(float4*)&pbuf[(size_t)ks * NTOT + idx + 4] =
                make_float4(acc[j * 8 + 4], acc[j * 8 + 5], acc[j * 8 + 6], acc[j * 8 + 7]);
        }
    }
}

// ===========================================================================
// conv_l2b: 128->128 @8x8 stride1 + 1x1/s2 shortcut. KS=16/CC=8.
// Shortcut global loads register-prefetched before main compute.
// ===========================================================================
template<int KS>
__global__ __launch_bounds__(256) void conv_l2b(
    const float* __restrict__ in,      // [32,128,8,8]
    const float* __restrict__ w,       // [128,128,3,3]
    const float* __restrict__ sc_in,   // [32,64,16,16]
    const float* __restrict__ sc_w,    // [128,64]
    float* __restrict__ pbuf)
{
    constexpr int CI = 128, CO = 128, SC_CI = 64;
    constexpr int CC  = CI / KS;
    constexpr int SCC = SC_CI / KS;
    constexpr int BSTR = 52, CST = 32 * BSTR;
    constexpr int BSTRs = 36, CSTs = 32 * BSTRs;
    constexpr int NTOT = 32 * CO * 64;
    constexpr int NSC  = SCC * 32 * 16;         // float4 count (2048 @ KS=16)
    constexpr int PFS  = (NSC + 255) / 256;     // 8
    __shared__ float sBuf[CC * CST];

    const int tid  = threadIdx.x;
    const int lane = tid & 63;
    const int b    = lane >> 1;
    const int co_u = __builtin_amdgcn_readfirstlane(blockIdx.y * 4 + (tid >> 6));
    const int ks   = blockIdx.x;
    const int r0   = blockIdx.z * 4;

    for (int i = tid; i < CC * 32 * 12; i += 256) {
        int f4  = i % 2;
        int row = (i / 2) % 6;
        int bb  = (i / 12) % 32;
        int c   = i / 384;
        int gr  = r0 - 1 + row;
        float4 v = make_float4(0.f, 0.f, 0.f, 0.f);
        if ((unsigned)gr < 8u)
            v = ld4(&in[(((size_t)bb * CI + ks * CC + c) * 8 + gr) * 8 + f4 * 4]);
        *(float4*)&sBuf[c * CST + bb * BSTR + row * 8 + f4 * 4] = v;
    }
    // issue shortcut global loads now (latency hidden under main compute)
    float4 scpf[PFS];
    #pragma unroll
    for (int k = 0; k < PFS; ++k) {
        int i = tid + k * 256;
        int q   = i % 4;
        int row = (i / 4) % 4;
        int bb  = (i / 16) % 32;
        int c   = i / 512;
        scpf[k] = ld4(&sc_in[
            (((size_t)bb * SC_CI + ks * SCC + c) * 16 + 2 * (r0 + row)) * 16 + q * 4]);
    }
    __syncthreads();

    float acc[32] = {};
    #pragma unroll 2
    for (int c = 0; c < CC; ++c) {
        const float* wk = w + ((size_t)co_u * CI + ks * CC + c) * 9;  // s_load
        float wr[9];
        #pragma unroll
        for (int q = 0; q < 9; ++q) wr[q] = wk[q];
        float pl[48];
        #pragma unroll
        for (int k = 0; k < 12; ++k) {
            float4 v = ld4(&sBuf[c * CST + b * BSTR + k * 4]);
            pl[k * 4 + 0] = v.x; pl[k * 4 + 1] = v.y;
            pl[k * 4 + 2] = v.z; pl[k * 4 + 3] = v.w;
        }
        #pragma unroll
        for (int oh = 0; oh < 4; ++oh) {
            #pragma unroll
            for (int ow = 0; ow < 8; ++ow) {
                #pragma unroll
                for (int kh = 0; kh < 3; ++kh) {
                    #pragma unroll
                    for (int kw = 0; kw < 3; ++kw) {
                        const int iw = ow - 1 + kw;
                        if (iw < 0 || iw >= 8) continue;
                        acc[oh * 8 + ow] = fmaf(pl[(oh + kh) * 8 + iw],
                                                wr[kh * 3 + kw], acc[oh * 8 + ow]);
                    }
                }
            }
        }
    }
    __syncthreads();

    #pragma unroll
    for (int k = 0; k < PFS; ++k) {
        int i = tid + k * 256;
        int q   = i % 4;
        int row = (i / 4) % 4;
        int bb  = (i / 16) % 32;
        int c   = i / 512;
        sBuf[c * CSTs + bb * BSTRs + row * 8 + q * 2 + 0] = scpf[k].x;
        sBuf[c * CSTs + bb * BSTRs + row * 8 + q * 2 + 1] = scpf[k].z;
    }
    __syncthreads();

    #pragma unroll
    for (int c = 0; c < SCC; ++c) {
        float sw = sc_w[(size_t)co_u * SC_CI + ks * SCC + c];   // s_load
        #pragma unroll
        for (int p4 = 0; p4 < 8; ++p4) {
            float4 v = ld4(&sBuf[c * CSTs + b * BSTRs + p4 * 4]);
            acc[p4 * 4 + 0] = fmaf(v.x, sw, acc[p4 * 4 + 0]);
            acc[p4 * 4 + 1] = fmaf(v.y, sw, acc[p4 * 4 + 1]);
            acc[p4 * 4 + 2] = fmaf(v.z, sw, acc[p4 * 4 + 2]);
            acc[p4 * 4 + 3] = fmaf(v.w, sw, acc[p4 * 4 + 3]);
        }
    }

    if ((lane & 1) == 0) {
        #pragma unroll
        for (int oh = 0; oh < 4; ++oh) {
            const size_t idx = ((size_t)(b * CO + co_u) * 8 + r0 + oh) * 8;
            *(float4*)&pbuf[(size_t)ks * NTOT + idx]     =
                make_float4(acc[oh * 8 + 0], acc[oh * 8 + 1], acc[oh * 8 + 2], acc[oh * 8 + 3]);
            *(float4*)&pbuf[(size_t)ks * NTOT + idx + 4] =
                make_float4(acc[oh * 8 + 4], acc[oh * 8 + 5], acc[oh * 8 + 6], acc[oh * 8 + 7]);
        }
    }
}

// ===========================================================================
// conv_ks (l3a/l3b/l4a/l4b): K-SPLIT small-plane conv.
// ===========================================================================
template<int CI, int HIN, int STRIDE, int CO, int SC_CI, int SC_HIN,
         int KS, int COB>
__global__ __launch_bounds__(COB * 64) void conv_ks(
    const float* __restrict__ in, const float* __restrict__ w,
    const float* __restrict__ sc_in, const float* __restrict__ sc_w,
    float* __restrict__ pbuf)
{
    constexpr int NT   = COB * 64;
    constexpr int HOUT = (STRIDE == 2) ? HIN / 2 : HIN;
    constexpr int P    = HOUT * HOUT;
    constexpr int NPIX = HIN * HIN;
    constexpr int CC   = CI / KS;
    constexpr int SCC  = (SC_CI > 0) ? SC_CI / KS : 0;
    constexpr int BSTR = NPIX + (((NPIX / 4) % 2 == 0) ? 4 : 0);
    constexpr int CST  = 32 * BSTR;
    constexpr int BSTRs = P + (((P / 4) % 2 == 0) ? 4 : 0);
    constexpr int CSTs  = 32 * BSTRs;
    static_assert(CI % KS == 0, "ks split");
    static_assert(NPIX % 4 == 0 && P % 4 == 0, "vector widths");

    __shared__ float sIn[CC * CST];
    __shared__ float sSc[(SCC > 0) ? SCC * CSTs : 1];

    const int tid  = threadIdx.x;
    const int lane = tid & 63;
    const int b    = lane >> 1;
    const int ks   = blockIdx.x;
    const int co_u = __builtin_amdgcn_readfirstlane(blockIdx.y * COB + (tid >> 6));
    const int cb   = ks * CC;

    constexpr int NF4 = CC * 32 * (NPIX / 4);
    for (int i = tid; i < NF4; i += NT) {
        int k4 = i % (NPIX / 4);
        int c  = (i / (NPIX / 4)) % CC;
        int bb = i / ((NPIX / 4) * CC);
        float4 v = ld4(&in[((size_t)bb * CI + cb + c) * NPIX + k4 * 4]);
        *(float4*)&sIn[c * CST + bb * BSTR + k4 * 4] = v;
    }
    if constexpr (SCC > 0) {
        constexpr int NH  = HOUT / 2;
        constexpr int NSC = SCC * 32 * HOUT * NH;
        for (int i = tid; i < NSC; i += NT) {
            int hc = i % NH;
            int r  = (i / NH) % HOUT;
            int c  = (i / (NH * HOUT)) % SCC;
            int bb = i / (NH * HOUT * SCC);
            float4 v = ld4(&sc_in[
                ((size_t)(bb * SC_CI + ks * SCC + c) * SC_HIN + 2 * r) * SC_HIN
                + hc * 4]);
            sSc[c * CSTs + bb * BSTRs + r * HOUT + hc * 2 + 0] = v.x;
            sSc[c * CSTs + bb * BSTRs + r * HOUT + hc * 2 + 1] = v.z;
        }
    }
    __syncthreads();

    float acc[P] = {};

    const float* wbase = w + ((size_t)co_u * CI + cb) * 9;
    #pragma unroll 4
    for (int j = 0; j < CC; ++j) {
        float wr[9];
        #pragma unroll
        for (int q = 0; q < 9; ++q) wr[q] = wbase[j * 9 + q];
        float plane[NPIX];
        #pragma unroll
        for (int r4 = 0; r4 < NPIX / 4; ++r4) {
            float4 v = ld4(&sIn[j * CST + b * BSTR + r4 * 4]);
            plane[r4 * 4 + 0] = v.x; plane[r4 * 4 + 1] = v.y;
            plane[r4 * 4 + 2] = v.z; plane[r4 * 4 + 3] = v.w;
        }
        #pragma unroll
        for (int ho = 0; ho < HOUT; ++ho) {
            #pragma unroll
            for (int wo = 0; wo < HOUT; ++wo) {
                #pragma unroll
                for (int kh = 0; kh < 3; ++kh) {
                    const int ih = ho * STRIDE - 1 + kh;
                    if (ih < 0 || ih >= HIN) continue;
                    #pragma unroll
                    for (int kw = 0; kw < 3; ++kw) {
                        const int iw = wo * STRIDE - 1 + kw;
                        if (iw < 0 || iw >= HIN) continue;
                        acc[ho * HOUT + wo] =
                            fmaf(plane[ih * HIN + iw], wr[kh * 3 + kw],
                                 acc[ho * HOUT + wo]);
                    }
                }
            }
        }
    }

    if constexpr (SCC > 0) {
        const float* swb = sc_w + (size_t)co_u * SC_CI + ks * SCC;
        #pragma unroll 4
        for (int j = 0; j < SCC; ++j) {
            float sw = swb[j];
            #pragma unroll
            for (int p4 = 0; p4 < P / 4; ++p4) {
                float4 v = ld4(&sSc[j * CSTs + b * BSTRs + p4 * 4]);
                acc[p4 * 4 + 0] = fmaf(v.x, sw, acc[p4 * 4 + 0]);
                acc[p4 * 4 + 1] = fmaf(v.y, sw, acc[p4 * 4 + 1]);
                acc[p4 * 4 + 2] = fmaf(v.z, sw, acc[p4 * 4 + 2]);
                acc[p4 * 4 + 3] = fmaf(v.w, sw, acc[p4 * 4 + 3]);
            }
        }
    }

    if ((lane & 1) == 0) {
        float* pp = pbuf + (((size_t)ks * 32 + b) * CO + co_u) * P;
        #pragma unroll
        for (int p4 = 0; p4 < P / 4; ++p4)
            *(float4*)&pp[p4 * 4] = make_float4(acc[p4 * 4], acc[p4 * 4 + 1],
                                                acc[p4 * 4 + 2], acc[p4 * 4 + 3]);
    }
}

// LIF epilogue on a float4.
__device__ __forceinline__ void lif_store4(
    float4 s, float* __restrict__ mem, const float* __restrict__ mask,
    float* __restrict__ out, float* __restrict__ accum,
    size_t idx, float thr, float leak)
{
    float4 m4 = ld4(&mem[idx]);
    float4 k4 = mask ? ld4(&mask[idx]) : make_float4(1.f, 1.f, 1.f, 1.f);
    float4 mo, oo;
    float m0 = fmaf(leak, m4.x, s.x); float s0 = (m0 / thr - 1.0f > 0.f) ? 1.f : 0.f;
    mo.x = m0 - thr * s0; oo.x = s0 * k4.x;
    float m1 = fmaf(leak, m4.y, s.y); float s1 = (m1 / thr - 1.0f > 0.f) ? 1.f : 0.f;
    mo.y = m1 - thr * s1; oo.y = s1 * k4.y;
    float m2 = fmaf(leak, m4.z, s.z); float s2 = (m2 / thr - 1.0f > 0.f) ? 1.f : 0.f;
    mo.z = m2 - thr * s2; oo.z = s2 * k4.z;
    float m3 = fmaf(leak, m4.w, s.w); float s3 = (m3 / thr - 1.0f > 0.f) ? 1.f : 0.f;
    mo.w = m3 - thr * s3; oo.w = s3 * k4.w;
    *(float4*)&mem[idx] = mo;
    *(float4*)&out[idx] = oo;
    if (accum) {
        float4 a4 = ld4(&accum[idx]);
        a4.x += oo.x; a4.y += oo.y; a4.z += oo.z; a4.w += oo.w;
        *(float4*)&accum[idx] = a4;
    }
}

// Sum KS partials (fixed order) + optional residual + LIF + mask + accum.
template<int CO, int P, int KS>
__global__ __launch_bounds__(256) void reduce_lif(
    const float* __restrict__ pbuf,
    const float* __restrict__ res,
    float* __restrict__ mem,
    const float* __restrict__ thr_a, const float* __restrict__ leak_a, int layer,
    const float* __restrict__ mask, float* __restrict__ out,
    float* __restrict__ accum)
{
    constexpr int TOT4 = 32 * CO * P / 4;
    const int i4 = blockIdx.x * 256 + threadIdx.x;
    if (i4 >= TOT4) return;
    const float4* pb4 = (const float4*)pbuf;
    float4 s = pb4[i4];
    #pragma unroll 4
    for (int ks = 1; ks < KS; ++ks) {
        float4 v = pb4[(size_t)ks * TOT4 + i4];
        s.x += v.x; s.y += v.y; s.z += v.z; s.w += v.w;
    }
    const size_t idx = (size_t)i4 * 4;
    if (res) {
        float4 r4 = ld4(&res[idx]);
        s.x += r4.x; s.y += r4.y; s.z += r4.z; s.w += r4.w;
    }
    lif_store4(s, mem, mask, out, accum, idx, thr_a[layer], leak_a[layer]);
}

// pre2 reducer: reduce KS partials + LIF (no mask) + fused 2x2 avgpool.
template<int KS>
__global__ __launch_bounds__(256) void reduce_lif_pool(
    const float* __restrict__ pbuf, float* __restrict__ mem,
    const float* __restrict__ thr_a, const float* __restrict__ leak_a, int layer,
    float* __restrict__ pool_out)             // [32,64,16,16]
{
    constexpr int TOT = 32 * 64 * 32 * 32;
    const int i = blockIdx.x * 256 + threadIdx.x;
    const int q  = i % 8;
    const int rp = (i / 8) % 16;
    const int c  = (i / 128) % 64;
    const int b  = i / 8192;
    const size_t idx0 = (((size_t)(b * 64 + c) * 32) + 2 * rp) * 32 + 4 * q;
    const size_t idx1 = idx0 + 32;

    float4 s0 = ld4(&pbuf[idx0]);
    float4 s1 = ld4(&pbuf[idx1]);
    #pragma unroll 4
    for (int ks = 1; ks < KS; ++ks) {
        float4 v0 = ld4(&pbuf[(size_t)ks * TOT + idx0]);
        float4 v1 = ld4(&pbuf[(size_t)ks * TOT + idx1]);
        s0.x += v0.x; s0.y += v0.y; s0.z += v0.z; s0.w += v0.w;
        s1.x += v1.x; s1.y += v1.y; s1.z += v1.z; s1.w += v1.w;
    }
    const float thr  = thr_a[layer];
    const float leak = leak_a[layer];
    float4 m0 = ld4(&mem[idx0]), m1 = ld4(&mem[idx1]);
    float4 n0, n1, o0, o1;
    {
        float m = fmaf(leak, m0.x, s0.x); float sp = (m / thr - 1.0f > 0.f) ? 1.f : 0.f;
        n0.x = m - thr * sp; o0.x = sp;
        m = fmaf(leak, m0.y, s0.y); sp = (m / thr - 1.0f > 0.f) ? 1.f : 0.f;
        n0.y = m - thr * sp; o0.y = sp;
        m = fmaf(leak, m0.z, s0.z); sp = (m / thr - 1.0f > 0.f) ? 1.f : 0.f;
        n0.z = m - thr * sp; o0.z = sp;
        m = fmaf(leak, m0.w, s0.w); sp = (m / thr - 1.0f > 0.f) ? 1.f : 0.f;
        n0.w = m - thr * sp; o0.w = sp;
        m = fmaf(leak, m1.x, s1.x); sp = (m / thr - 1.0f > 0.f) ? 1.f : 0.f;
        n1.x = m - thr * sp; o1.x = sp;
        m = fmaf(leak, m1.y, s1.y); sp = (m / thr - 1.0f > 0.f) ? 1.f : 0.f;
        n1.y = m - thr * sp; o1.y = sp;
        m = fmaf(leak, m1.z, s1.z); sp = (m / thr - 1.0f > 0.f) ? 1.f : 0.f;
        n1.z = m - thr * sp; o1.z = sp;
        m = fmaf(leak, m1.w, s1.w); sp = (m / thr - 1.0f > 0.f) ? 1.f : 0.f;
        n1.w = m - thr * sp; o1.w = sp;
    }
    *(float4*)&mem[idx0] = n0;
    *(float4*)&mem[idx1] = n1;
    float2 pv;
    pv.x = (o0.x + o0.y + o1.x + o1.y) * 0.25f;
    pv.y = (o0.z + o0.w + o1.z + o1.w) * 0.25f;
    *(float2*)&pool_out[(((size_t)(b * 64 + c) * 16) + rp) * 16 + 2 * q] = pv;
}

// Merged: l4b reduce (blocks 0..63) + NEXT timestep's lif0 (blocks 64..2111).
template<int KS>
__global__ __launch_bounds__(256) void reduce_l4b_lif0(
    const float* __restrict__ pbuf, float* __restrict__ mem10,
    const float* __restrict__ thr_a, const float* __restrict__ leak_a,
    float* __restrict__ out_s2b, float* __restrict__ ssum,
    const float4* __restrict__ delta, float4* __restrict__ mem0,
    const float4* __restrict__ mask, float4* __restrict__ s32a)
{
    if (blockIdx.x < 64) {
        constexpr int TOT4 = 32 * 512;
        const int i4 = blockIdx.x * 256 + threadIdx.x;
        if (i4 >= TOT4) return;
        const float4* pb4 = (const float4*)pbuf;
        float4 s = pb4[i4];
        #pragma unroll 4
        for (int ks = 1; ks < KS; ++ks) {
            float4 v = pb4[(size_t)ks * TOT4 + i4];
            s.x += v.x; s.y += v.y; s.z += v.z; s.w += v.w;
        }
        lif_store4(s, mem10, nullptr, out_s2b, ssum,
                   (size_t)i4 * 4, thr_a[10], leak_a[10]);
    } else {
        const int i = (blockIdx.x - 64) * 256 + threadIdx.x;
        float thr = thr_a[0], leak = leak_a[0];
        float4 d = delta[i], m4 = mem0[i], k4 = mask[i], mo, oo;
        float m0 = fmaf(leak, m4.x, d.x); float s0 = (m0 / thr - 1.0f > 0.f) ? 1.f : 0.f;
        mo.x = m0 - thr * s0; oo.x = s0 * k4.x;
        float m1 = fmaf(leak, m4.y, d.y); float s1 = (m1 / thr - 1.0f > 0.f) ? 1.f : 0.f;
        mo.y = m1 - thr * s1; oo.y = s1 * k4.y;
        float m2 = fmaf(leak, m4.z, d.z); float s2 = (m2 / thr - 1.0f > 0.f) ? 1.f : 0.f;
        mo.z = m2 - thr * s2; oo.z = s2 * k4.z;
        float m3 = fmaf(leak, m4.w, d.w); float s3 = (m3 / thr - 1.0f > 0.f) ? 1.f : 0.f;
        mo.w = m3 - thr * s3; oo.w = s3 * k4.w;
        mem0[i] = mo; s32a[i] = oo;
    }
}

// ===========================================================================
// Naive direct conv — ONLY for pre0 (Ci=3, runs once per launch).
// ===========================================================================
__global__ __launch_bounds__(256) void conv_raw_kernel(
    const float* __restrict__ in, const float* __restrict__ w,
    float* __restrict__ out,
    int Ci, int Co, int Hin, int Win, int total)
{
    int idx = blockIdx.x * blockDim.x + threadIdx.x;
    if (idx >= total) return;
    int wo = idx % Win;
    int t  = idx / Win;
    int ho = t % Hin; t /= Hin;
    int co = t % Co;
    int b  = t / Co;
    int ih0 = ho - 1, iw0 = wo - 1;
    const float* wp = w + (size_t)co * Ci * 9;
    const float* ip = in + (size_t)b * Ci * Hin * Win;
    bool hv0 = (unsigned)(ih0)     < (unsigned)Hin;
    bool hv1 = (unsigned)(ih0 + 1) < (unsigned)Hin;
    bool hv2 = (unsigned)(ih0 + 2) < (unsigned)Hin;
    bool wv0 = (unsigned)(iw0)     < (unsigned)Win;
    bool wv1 = (unsigned)(iw0 + 1) < (unsigned)Win;
    bool wv2 = (unsigned)(iw0 + 2) < (unsigned)Win;
    float acc = 0.f;
    int plane = Hin * Win;
    for (int ci = 0; ci < Ci; ++ci) {
        const float* irow = ip + ci * plane;
        const float* wk   = wp + ci * 9;
        if (hv0) {
            const float* r = irow + ih0 * Win;
            if (wv0) acc = fmaf(r[iw0],     wk[0], acc);
            if (wv1) acc = fmaf(r[iw0 + 1], wk[1], acc);
            if (wv2) acc = fmaf(r[iw0 + 2], wk[2], acc);
        }
        if (hv1) {
            const float* r = irow + (ih0 + 1) * Win;
            if (wv0) acc = fmaf(r[iw0],     wk[3], acc);
            if (wv1) acc = fmaf(r[iw0 + 1], wk[4], acc);
            if (wv2) acc = fmaf(r[iw0 + 2], wk[5], acc);
        }
        if (hv2) {
            const float* r = irow + (ih0 + 2) * Win;
            if (wv0) acc = fmaf(r[iw0],     wk[6], acc);
            if (wv1) acc = fmaf(r[iw0 + 1], wk[7], acc);
            if (wv2) acc = fmaf(r[iw0 + 2], wk[8], acc);
        }
    }
    out[idx] = acc;
}

// Elementwise LIF for layer 0 — standalone (t=0 only).
__global__ __launch_bounds__(256) void lif0_kernel(
    const float4* __restrict__ delta, float4* __restrict__ mem,
    const float* __restrict__ thr_a, const float* __restrict__ leak_a,
    const float4* __restrict__ mask, float4* __restrict__ out, int total4)
{
    int i = blockIdx.x * blockDim.x + threadIdx.x;
    if (i >= total4) return;
    float thr = thr_a[0], leak = leak_a[0];
    float4 d = delta[i], m4 = mem[i], k4 = mask[i], mo, oo;
    float m0 = fmaf(leak, m4.x, d.x); float s0 = (m0 / thr - 1.0f > 0.f) ? 1.f : 0.f;
    mo.x = m0 - thr * s0; oo.x = s0 * k4.x;
    float m1 = fmaf(leak, m4.y, d.y); float s1 = (m1 / thr - 1.0f > 0.f) ? 1.f : 0.f;
    mo.y = m1 - thr * s1; oo.y = s1 * k4.y;
    float m2 = fmaf(leak, m4.z, d.z); float s2 = (m2 / thr - 1.0f > 0.f) ? 1.f : 0.f;
    mo.z = m2 - thr * s2; oo.z = s2 * k4.z;
    float m3 = fmaf(leak, m4.w, d.w); float s3 = (m3 / thr - 1.0f > 0.f) ? 1.f : 0.f;
    mo.w = m3 - thr * s3; oo.w = s3 * k4.w;
    mem[i] = mo; out[i] = oo;
}

// FC: out[b,k] = dot(spikesum[b, :2048], wfc[k, :2048]). One wave per (b,k).
__global__ __launch_bounds__(64) void fc_kernel(
    const float* __restrict__ s, const float* __restrict__ wfc,
    float* __restrict__ out)
{
    int bk = blockIdx.x;
    int b = bk / 10, k = bk % 10;
    const float* sp = s   + (size_t)b * 2048;
    const float* wp = wfc + (size_t)k * 2048;
    float acc = 0.f;
    for (int j = threadIdx.x; j < 2048; j += 64)
        acc = fmaf(sp[j], wp[j], acc);
    #pragma unroll
    for (int off = 32; off; off >>= 1)
        acc += __shfl_down(acc, off, 64);
    if (threadIdx.x == 0) out[b * 10 + k] = acc;
}

// ---------------------------------------------------------------------------
extern "C" void kernel_launch(void* const* d_in, const int* in_sizes, int n_in,
                              void* d_out, int out_size, void* d_ws, size_t ws_size,
                              hipStream_t stream) {
    const float* x      = (const float*)d_in[0];
    const float* w_pre0 = (const float*)d_in[1];
    const float* w_pre1 = (const float*)d_in[2];
    const float* w_pre2 = (const float*)d_in[3];
    const float* w1a    = (const float*)d_in[4];
    const float* w1b    = (const float*)d_in[5];
    const float* w2a    = (const float*)d_in[6];
    const float* w2b    = (const float*)d_in[7];
    const float* w2i    = (const float*)d_in[8];
    const float* w3a    = (const float*)d_in[9];
    const float* w3b    = (const float*)d_in[10];
    const float* w3i    = (const float*)d_in[11];
    const float* w4a    = (const float*)d_in[12];
    const float* w4b    = (const float*)d_in[13];
    const float* w4i    = (const float*)d_in[14];
    const float* w_fc   = (const float*)d_in[15];
    const float* thr    = (const float*)d_in[16];
    const float* leak   = (const float*)d_in[17];
    const float* mask2  = (const float*)d_in[18];
    const float* mask5  = (const float*)d_in[19];
    const float* mask9  = (const float*)d_in[20];
    const float* mask11 = (const float*)d_in[21];
    const float* mask13 = (const float*)d_in[22];
    const float* mask15 = (const float*)d_in[23];

    // ---- workspace layout (floats) ----
    float* ws = (float*)d_ws;
    size_t off = 0;
    auto alloc = [&](size_t n) { float* p = ws + off; off += n; return p; };
    float* m0  = alloc(2097152);  // 32*64*32*32
    float* m1  = alloc(2097152);
    float* m2  = alloc(2097152);
    float* m3  = alloc(524288);   // 32*64*16*16
    float* m4  = alloc(524288);
    float* m5  = alloc(262144);   // 32*128*8*8
    float* m6  = alloc(262144);
    float* m7  = alloc(131072);   // 32*256*4*4
    float* m8  = alloc(131072);
    float* m9  = alloc(65536);    // 32*512*2*2
    float* m10 = alloc(65536);
    float* ssum = alloc(65536);   // fc spike accumulator (32 x 2048)
    size_t zero_floats = off;
    float* delta0  = alloc(2097152);
    float* s32_a   = alloc(2097152);
    float* s32_b   = alloc(2097152);
    float* s16_inp = alloc(524288);
    float* s16_a   = alloc(524288);
    float* s16_b   = alloc(524288);
    float* s8_a    = alloc(262144);
    float* s8_b    = alloc(262144);
    float* s4_a    = alloc(131072);
    float* s4_b    = alloc(131072);
    float* s2_a    = alloc(65536);
    float* s2_b    = alloc(65536);
    float* pbuf    = alloc(16777216);  // K-split partials
    (void)ws_size; (void)in_sizes; (void)n_in; (void)out_size;

    hipMemsetAsync(d_ws, 0, zero_floats * sizeof(float), stream);

    auto grid = [](int total) { return dim3((total + 255) / 256); };

    // timestep-invariant: delta0 = conv(x, w_pre0)
    {
        int total = BATCH * 64 * 32 * 32;
        conv_raw_kernel<<<grid(total), 256, 0, stream>>>(
            x, w_pre0, delta0, 3, 64, 32, 32, total);
    }

    int n32 = BATCH * 64 * 32 * 32;
    // t=0 lif0 (standalone; t>=1 lif0 is fused into prior l4b reduce)
    lif0_kernel<<<grid(n32 / 4), 256, 0, stream>>>(
        (const float4*)delta0, (float4*)m0, thr, leak,
        (const float4*)mask2, (float4*)s32_a, n32 / 4);

    for (int t = 0; t < 8; ++t) {
        // pre1: 64->64 @32x32 + LIF + mask5  (KS=4, pipelined, 256-thr blocks)
        conv64_v2<32, 4><<<dim3(BATCH, 4, 8), 256, 0, stream>>>(s32_a, w_pre1, pbuf);
        reduce_lif<64, 1024, 4><<<dim3(2048), 256, 0, stream>>>(
            pbuf, nullptr, m1, thr, leak, 1, mask5, s32_b, nullptr);
        // pre2: 64->64 @32x32 + LIF + fused avgpool -> s16_inp
        conv64_v2<32, 4><<<dim3(BATCH, 4, 8), 256, 0, stream>>>(s32_b, w_pre2, pbuf);
        reduce_lif_pool<4><<<dim3(1024), 256, 0, stream>>>(
            pbuf, m2, thr, leak, 2, s16_inp);
        // layer1 a: 64->64 @16x16 + LIF + mask9  (KS=8)
        conv64_v2<16, 8><<<dim3(BATCH, 1, 16), 256, 0, stream>>>(s16_inp, w1a, pbuf);
        reduce_lif<64, 256, 8><<<dim3(512), 256, 0, stream>>>(
            pbuf, nullptr, m3, thr, leak, 3, mask9, s16_a, nullptr);
        // layer1 b: 64->64 @16x16 + identity residual + LIF  (KS=8)
        conv64_v2<16, 8><<<dim3(BATCH, 1, 16), 256, 0, stream>>>(s16_a, w1b, pbuf);
        reduce_lif<64, 256, 8><<<dim3(512), 256, 0, stream>>>(
            pbuf, s16_inp, m4, thr, leak, 4, nullptr, s16_b, nullptr);

        // layer2 a: 64->128 s2 @16->8 + LIF + mask11  (conv_mid, KS=32, RT=2)
        conv_mid<64, 128, 32, 2><<<dim3(32, 32, 4), 256, 0, stream>>>(
            s16_b, w2a, pbuf);
        reduce_lif<128, 64, 32><<<dim3(256), 256, 0, stream>>>(
            pbuf, nullptr, m5, thr, leak, 5, mask11, s8_a, nullptr);
        // layer2 b: 128->128 @8x8 + 1x1/s2 shortcut + LIF  (KS=16, sc prefetch)
        conv_l2b<16><<<dim3(16, 32, 2), 256, 0, stream>>>(
            s8_a, w2b, s16_b, w2i, pbuf);
        reduce_lif<128, 64, 16><<<dim3(256), 256, 0, stream>>>(
            pbuf, nullptr, m6, thr, leak, 6, nullptr, s8_b, nullptr);
        // layer3 a: 128->256 s2 @8->4 + LIF + mask13  (K-split 32)
        conv_ks<128, 8, 2, 256, 0, 0, 32, 4><<<dim3(32, 64), 256, 0, stream>>>(
            s8_b, w3a, nullptr, nullptr, pbuf);
        reduce_lif<256, 16, 32><<<dim3(128), 256, 0, stream>>>(
            pbuf, nullptr, m7, thr, leak, 7, mask13, s4_a, nullptr);
        // layer3 b: 256->256 @4x4 + 1x1/s2 shortcut + LIF  (K-split 16)
        conv_ks<256, 4, 1, 256, 128, 8, 16, 4><<<dim3(16, 64), 256, 0, stream>>>(
            s4_a, w3b, s8_b, w3i, pbuf);
        reduce_lif<256, 16, 16><<<dim3(128), 256, 0, stream>>>(
            pbuf, nullptr, m8, thr, leak, 8, nullptr, s4_b, nullptr);
        // layer4 a: 256->512 s2 @4->2 + LIF + mask15  (K-split 16)
        conv_ks<256, 4, 2, 512, 0, 0, 16, 4><<<dim3(16, 128), 256, 0, stream>>>(
            s4_b, w4a, nullptr, nullptr, pbuf);
        reduce_lif<512, 4, 16><<<dim3(64), 256, 0, stream>>>(
            pbuf, nullptr, m9, thr, leak, 9, mask15, s2_a, nullptr);
        // layer4 b: 512->512 @2x2 + 1x1/s2 shortcut + LIF + spike-sum (K-split 16)
        conv_ks<512, 2, 1, 512, 256, 4, 16, 4><<<dim3(16, 128), 256, 0, stream>>>(
            s2_a, w4b, s4_b, w4i, pbuf);
        if (t < 7) {
            reduce_l4b_lif0<16><<<dim3(64 + 2048), 256, 0, stream>>>(
                pbuf, m10, thr, leak, s2_b, ssum,
                (const float4*)delta0, (float4*)m0, (const float4*)mask2,
                (float4*)s32_a);
        } else {
            reduce_lif<512, 4, 16><<<dim3(64), 256, 0, stream>>>(
                pbuf, nullptr, m10, thr, leak, 10, nullptr, s2_b, ssum);
        }
    }

    // final FC: d_out[b,k] = dot(ssum[b], w_fc[k])
    fc_kernel<<<dim3(320), dim3(64), 0, stream>>>(ssum, w_fc, (float*)d_out);
}